// Round 7
// baseline (340.659 us; speedup 1.0000x reference)
//
#include <hip/hip_runtime.h>
#include <hip/hip_cooperative_groups.h>
#include <stdint.h>

namespace cg = cooperative_groups;

typedef unsigned int u32;
typedef unsigned long long u64;
typedef unsigned short us;
using short8 = __attribute__((ext_vector_type(8))) short;
using us4    = __attribute__((ext_vector_type(4))) us;
using us8    = __attribute__((ext_vector_type(8))) us;
using f32x4  = __attribute__((ext_vector_type(4))) float;

#define BT 16
#define NPT 1024

struct Params {
    const float *xyz, *pts;
    const float *w1a, *b1a, *w1b, *b1b, *w1c, *b1c;
    const float *w2a, *b2a, *w2b, *b2b, *w2c, *b2c;
    u64* keys;
    us *wf1a, *wf1b, *wf1c, *wf2a, *wf2b, *wf2c, *newbf;
    float* outp;
};

// ---------- bf16 helpers ----------
__device__ __forceinline__ us f2bf(float f) {           // RNE f32 -> bf16
    u32 u = __float_as_uint(f);
    u += 0x7fffu + ((u >> 16) & 1u);
    return (us)(u >> 16);
}

// ---------- select unit: 2-pass shortlist, u64 atomicMin merge ----------
// sm layout: sx[192] f32 | sn[256][3] f32 | lst[4][4096] us   (36608 B)
__device__ void select_unit(int u, const float* __restrict__ xyz,
                            u64* __restrict__ keys, char* sm) {
    float* sx = (float*)sm;
    float* sn = (float*)(sm + 768);
    us* lst = (us*)(sm + 768 + 3072);
    const int t = threadIdx.x;
    const int b = u >> 6, chunk = (u >> 2) & 15, nb = u & 3;
    const int j0 = chunk * 64;
    __syncthreads();                                   // sm reuse guard
    const float* xb = xyz + (size_t)b * 3072;
    if (t < 192) sx[t] = xb[(size_t)j0 * 3 + t];
    const int n = nb * 256 + t;                        // n within batch
    const int lane = t & 63, wid = t >> 6;
    const float xn = xb[n * 3 + 0], yn = xb[n * 3 + 1], zn = xb[n * 3 + 2];
    float* snp = sn + t * 3;
    snp[0] = xn; snp[1] = yn; snp[2] = zn;
    __syncthreads();

    // pass 1: distance + validity only, wave-compact shortlist
    us* wl = lst + wid * 4096;
    u32 cnt = 0;
    for (int jj = 0; jj < 64; ++jj) {
        float dx = __fadd_rn(sx[jj * 3 + 0], -xn);
        float dy = __fadd_rn(sx[jj * 3 + 1], -yn);
        float dz = __fadd_rn(sx[jj * 3 + 2], -zn);
        // exact IEEE f32, no contraction: must match numpy bit-for-bit
        float d = __fadd_rn(__fadd_rn(__fmul_rn(dx, dx), __fmul_rn(dy, dy)), __fmul_rn(dz, dz));
        bool valid = (d > 1e-10f) && (d < 0.04f);
        u64 m = __ballot(valid);
        if (valid) {
            u32 off = __builtin_amdgcn_mbcnt_lo((u32)m, 0);
            off = __builtin_amdgcn_mbcnt_hi((u32)(m >> 32), off);
            wl[cnt + off] = (us)((lane << 6) | jj);
        }
        cnt += (u32)__popcll(m);
    }

    // pass 2: balanced over lanes; exact recompute + direct atomicMin
    const int n0w = nb * 256 + wid * 64;
    u64* kb = keys + (((size_t)b << 10) << 3);
    for (u32 i = lane; i < cnt; i += 64) {
        u32 e = wl[i];
        int nl = e >> 6, jj = e & 63;
        const float* sp = sn + (wid * 64 + nl) * 3;
        float dx = __fadd_rn(sx[jj * 3 + 0], -sp[0]);
        float dy = __fadd_rn(sx[jj * 3 + 1], -sp[1]);
        float dz = __fadd_rn(sx[jj * 3 + 2], -sp[2]);
        float d = __fadd_rn(__fadd_rn(__fmul_rn(dx, dx), __fmul_rn(dy, dy)), __fmul_rn(dz, dz));
        int oct = ((int)__fadd_rn(dx, 1.0f)) * 4 + ((int)__fadd_rn(dy, 1.0f)) * 2 +
                  ((int)__fadd_rn(dz, 1.0f));
        u64 key = ((u64)__float_as_uint(d) << 32) | (u32)(j0 + jj);
        atomicMin(&kb[((size_t)(n0w + nl) << 3) + oct], key);
    }

    if (chunk == 0) {                                  // self-fallback keys
        u64 selfkey = ((u64)__float_as_uint(0.04f) << 32) | (u32)n;
        u64* kp = kb + ((size_t)n << 3);
#pragma unroll
        for (int o = 0; o < 8; ++o) atomicMin(&kp[o], selfkey);
    }
}

// ---------- weight -> MFMA B-fragment order ----------
__device__ void wprep_unit(int u2, const Params& p) {
    const float* w; us* dst; int Kreal, base;
    if (u2 < 10)      { w = p.w1a; dst = p.wf1a; Kreal = 134; base = 0;  }
    else if (u2 < 26) { w = p.w1b; dst = p.wf1b; Kreal = 256; base = 10; }
    else if (u2 < 42) { w = p.w1c; dst = p.wf1c; Kreal = 256; base = 26; }
    else if (u2 < 60) { w = p.w2a; dst = p.wf2a; Kreal = 262; base = 42; }
    else if (u2 < 76) { w = p.w2b; dst = p.wf2b; Kreal = 256; base = 60; }
    else              { w = p.w2c; dst = p.wf2c; Kreal = 256; base = 76; }
    int tid = (u2 - base) * 256 + threadIdx.x;
    int lane = tid & 63, ct = (tid >> 6) & 7, kt = tid >> 9;
    int o = ct * 16 + (lane & 15);
    int k0 = kt * 32 + ((lane >> 4) << 3);
    us8 v;
#pragma unroll
    for (int j = 0; j < 8; ++j) {
        int k = k0 + j;
        v[j] = (k < Kreal) ? f2bf(w[(size_t)o * Kreal + k]) : (us)0;
    }
    *(us8*)(dst + (size_t)tid * 8) = v;
}

// ---------- per-thread register gather of one 16B A-fragment chunk ----------
template<int S>
__device__ __forceinline__ short8 gatherA(int c0, int j0, int j1, int n,
                                          const float* __restrict__ xb,
                                          const float* __restrict__ pts_b,
                                          const us* __restrict__ new_b) {
    short8 v;
    if constexpr (S == 1) {
#pragma unroll
        for (int jj = 0; jj < 4; ++jj) {
            int c = c0 + jj;
            float f0, f1;
            if (c < 3) {
                f0 = __fadd_rn(xb[j0 * 3 + c], -xb[n * 3 + c]);
                f1 = __fadd_rn(xb[j1 * 3 + c], -xb[n * 3 + c]);
            } else if (c < 67) {
                f0 = pts_b[(size_t)(j0 << 6) + c - 3];
                f1 = pts_b[(size_t)(j1 << 6) + c - 3];
            } else { f0 = 0.f; f1 = 0.f; }
            v[2 * jj]     = (short)f2bf(f0);
            v[2 * jj + 1] = (short)f2bf(f1);
        }
    } else {
        const us* rp0 = new_b + (size_t)j0 * 136;
        const us* rp1 = new_b + (size_t)j1 * 136;
        if (c0 == 0) {
#pragma unroll
            for (int jj = 0; jj < 3; ++jj) {
                float f0 = __fadd_rn(xb[j0 * 3 + jj], -xb[n * 3 + jj]);
                float f1 = __fadd_rn(xb[j1 * 3 + jj], -xb[n * 3 + jj]);
                v[2 * jj]     = (short)f2bf(f0);
                v[2 * jj + 1] = (short)f2bf(f1);
            }
            v[6] = (short)rp0[3];
            v[7] = (short)rp1[3];
        } else if (c0 <= 128) {
            us4 a0 = *(const us4*)(rp0 + c0);      // 8B aligned (c0 % 4 == 0, stride 136)
            us4 a1 = *(const us4*)(rp1 + c0);
            if (c0 == 128) { a0[3] = 0; a1[3] = 0; }   // channel 131 is K-padding
#pragma unroll
            for (int jj = 0; jj < 4; ++jj) {
                v[2 * jj]     = (short)a0[jj];
                v[2 * jj + 1] = (short)a1[jj];
            }
        } else {
            v = short8{0, 0, 0, 0, 0, 0, 0, 0};
        }
    }
    return v;
}

// ---------- fused stage unit: gather -> conv-a -> conv-b -> conv-c ----------
template<int S>
__device__ void stage_unit(int u, const Params& p, char* sm) {
    constexpr int KTA = (S == 1) ? 5 : 9;
    us* abuf = (us*)sm;                  // 16KB
    us* cbuf = (us*)(sm + 16384);        // 8KB
    const us* wfa    = (S == 1) ? p.wf1a : p.wf2a;
    const float* ba  = (S == 1) ? p.b1a  : p.b2a;
    const us* wfb    = (S == 1) ? p.wf1b : p.wf2b;
    const float* bb  = (S == 1) ? p.b1b  : p.b2b;
    const us* wfc    = (S == 1) ? p.wf1c : p.wf2c;
    const float* bc  = (S == 1) ? p.b1c  : p.b2c;

    const int t = threadIdx.x, wid = t >> 6, lane = t & 63;
    const int li = lane & 15, h = lane >> 4;
    const int m0 = u * 64;               // conv-a global row base
    const int g0 = u * 16;               // 16 groups per unit
    const int b = u >> 6;
    const float* xb = p.xyz + (size_t)b * 3072;
    const float* pts_b = p.pts + ((size_t)b << 16);
    const us* new_b = p.newbf + (size_t)b * NPT * 136;
    const u32* keys32 = (const u32*)p.keys;

    const int m = m0 + wid * 16 + li;
    const int g = m >> 2, pos = m & 3;
    const int J0 = (int)keys32[((size_t)g * 8 + 2 * pos) * 2];
    const int J1 = (int)keys32[((size_t)g * 8 + 2 * pos + 1) * 2];
    const int N = g & (NPT - 1);

    __syncthreads();                      // sm reuse guard

    // ---- conv-a: register gather + MFMA (1 m-tile per wave) ----
    f32x4 acc[8];
#pragma unroll
    for (int j = 0; j < 8; ++j) acc[j] = f32x4{0.f, 0.f, 0.f, 0.f};
    for (int kt = 0; kt < KTA; ++kt) {    // not unrolled: stay under 128 VGPR
        short8 a = gatherA<S>(kt * 16 + h * 4, J0, J1, N, xb, pts_b, new_b);
        const us* wk = wfa + (size_t)kt * 8 * 512;
#pragma unroll
        for (int ct = 0; ct < 8; ++ct) {
            short8 w = *(const short8*)(wk + ((size_t)ct * 64 + lane) * 8);
            acc[ct] = __builtin_amdgcn_mfma_f32_16x16x32_bf16(a, w, acc[ct], 0, 0, 0);
        }
    }
    {   // pair-transpose epilogue -> abuf (validated formula, local rows 0..63)
        u32* dst = (u32*)abuf;
        int mbase = wid * 16 + (h << 2);
        int mr0 = mbase >> 1, mr1 = mr0 + 1;
#pragma unroll
        for (int ct = 0; ct < 8; ++ct) {
            int o = ct * 16 + li;
            float bv = ba[o];
            f32x4 av = acc[ct];
            u32 p0 = (u32)f2bf(av[0] + bv) | ((u32)f2bf(av[1] + bv) << 16);
            u32 p1 = (u32)f2bf(av[2] + bv) | ((u32)f2bf(av[3] + bv) << 16);
            dst[((mr0 >> 4) * 8 + ct) * 256 + ((mr0 & 15) + ((li >> 2) << 4)) * 4 + (li & 3)] = p0;
            dst[((mr1 >> 4) * 8 + ct) * 256 + ((mr1 & 15) + ((li >> 2) << 4)) * 4 + (li & 3)] = p1;
        }
    }
    __syncthreads();

    // ---- conv-b: wave -> m-tile (wid>>1), ct block (wid&1)*4..+3 ----
    const int mtB = wid >> 1, ctbB = (wid & 1) * 4;
    f32x4 accB[4];
#pragma unroll
    for (int j = 0; j < 4; ++j) accB[j] = f32x4{0.f, 0.f, 0.f, 0.f};
    for (int kt = 0; kt < 8; ++kt) {
        short8 a = *(const short8*)(abuf + (((size_t)mtB * 8 + kt) * 64 + lane) * 8);
        const us* wk = wfb + ((size_t)kt * 8 + ctbB) * 512;
#pragma unroll
        for (int cc = 0; cc < 4; ++cc) {
            short8 w = *(const short8*)(wk + ((size_t)cc * 64 + lane) * 8);
            accB[cc] = __builtin_amdgcn_mfma_f32_16x16x32_bf16(a, w, accB[cc], 0, 0, 0);
        }
    }
    {   // -> cbuf (conv-c rows 0..15, single m-tile)
        u32* dst = (u32*)cbuf;
        int mbase = mtB * 16 + (h << 2);
        int mr0 = mbase >> 1, mr1 = mr0 + 1;
#pragma unroll
        for (int cc = 0; cc < 4; ++cc) {
            int ct = ctbB + cc;
            int o = ct * 16 + li;
            float bv = bb[o];
            f32x4 av = accB[cc];
            u32 p0 = (u32)f2bf(av[0] + bv) | ((u32)f2bf(av[1] + bv) << 16);
            u32 p1 = (u32)f2bf(av[2] + bv) | ((u32)f2bf(av[3] + bv) << 16);
            dst[ct * 256 + (mr0 + ((li >> 2) << 4)) * 4 + (li & 3)] = p0;
            dst[ct * 256 + (mr1 + ((li >> 2) << 4)) * 4 + (li & 3)] = p1;
        }
    }
    __syncthreads();

    // ---- conv-c: wave -> ct pair wid*2..+1, single m-tile ----
    f32x4 accC[2];
#pragma unroll
    for (int j = 0; j < 2; ++j) accC[j] = f32x4{0.f, 0.f, 0.f, 0.f};
    for (int kt = 0; kt < 8; ++kt) {
        short8 a = *(const short8*)(cbuf + ((size_t)kt * 64 + lane) * 8);
        const us* wk = wfc + ((size_t)kt * 8 + wid * 2) * 512;
#pragma unroll
        for (int cc = 0; cc < 2; ++cc) {
            short8 w = *(const short8*)(wk + ((size_t)cc * 64 + lane) * 8);
            accC[cc] = __builtin_amdgcn_mfma_f32_16x16x32_bf16(a, w, accC[cc], 0, 0, 0);
        }
    }
#pragma unroll
    for (int cc = 0; cc < 2; ++cc) {
        int o = (wid * 2 + cc) * 16 + li;
        float bv = bc[o];
#pragma unroll
        for (int r = 0; r < 4; ++r) {
            int gg = g0 + h * 4 + r;
            float val = accC[cc][r] + bv;
            if constexpr (S == 1)
                p.newbf[((size_t)b * NPT + 0) * 0 + (size_t)gg * 136 + 3 + o] = f2bf(val);
            else
                p.outp[(size_t)49152 + (size_t)gg * 192 + o] = fmaxf(val, 0.f);
        }
    }

    if constexpr (S == 2) {
        // relu(points) tail: 16 groups x 16 float4 each
        int r = t >> 4, q = t & 15;
        float4 v = ((const float4*)(p.pts + ((size_t)(g0 + r) << 6)))[q];
        v.x = fmaxf(v.x, 0.0f);
        v.y = fmaxf(v.y, 0.0f);
        v.z = fmaxf(v.z, 0.0f);
        v.w = fmaxf(v.w, 0.0f);
        *(float4*)(p.outp + 49152 + (size_t)(g0 + r) * 192 + 128 + q * 4) = v;
    }
}

// ---------- single cooperative kernel: select+prep -> stage1 -> stage2 ----------
__global__ __launch_bounds__(256, 4) void k_fused(Params p) {
    __shared__ __align__(16) char sm[36864];
    cg::grid_group grid = cg::this_grid();
    const int gsz = (int)gridDim.x;

    for (int u = blockIdx.x; u < 1164; u += gsz) {
        if (u < 1024) {
            select_unit(u, p.xyz, p.keys, sm);
        } else if (u < 1116) {
            wprep_unit(u - 1024, p);
        } else {                                        // xyz passthrough
            int id = (u - 1116) * 256 + threadIdx.x;
            ((float4*)p.outp)[id] = ((const float4*)p.xyz)[id];
        }
    }
    grid.sync();
    for (int u = blockIdx.x; u < 1024; u += gsz) stage_unit<1>(u, p, sm);
    grid.sync();
    for (int u = blockIdx.x; u < 1024; u += gsz) stage_unit<2>(u, p, sm);
}

extern "C" void kernel_launch(void* const* d_in, const int* in_sizes, int n_in,
                              void* d_out, int out_size, void* d_ws, size_t ws_size,
                              hipStream_t stream) {
    char* ws = (char*)d_ws;
    Params prm;
    prm.xyz = (const float*)d_in[0];
    prm.pts = (const float*)d_in[1];
    prm.w1a = (const float*)d_in[2];  prm.b1a = (const float*)d_in[3];
    prm.w1b = (const float*)d_in[4];  prm.b1b = (const float*)d_in[5];
    prm.w1c = (const float*)d_in[6];  prm.b1c = (const float*)d_in[7];
    prm.w2a = (const float*)d_in[8];  prm.b2a = (const float*)d_in[9];
    prm.w2b = (const float*)d_in[10]; prm.b2b = (const float*)d_in[11];
    prm.w2c = (const float*)d_in[12]; prm.b2c = (const float*)d_in[13];
    prm.keys  = (u64*)ws;                      // 1 MB
    prm.wf1a  = (us*)(ws + 1048576);           // 40 KB  (KT=5)
    prm.wf1b  = (us*)(ws + 1089536);           // 64 KB  (KT=8)
    prm.wf1c  = (us*)(ws + 1155072);           // 64 KB
    prm.wf2a  = (us*)(ws + 1220608);           // 72 KB  (KT=9)
    prm.wf2b  = (us*)(ws + 1294336);           // 64 KB
    prm.wf2c  = (us*)(ws + 1359872);           // 64 KB
    prm.newbf = (us*)(ws + 2097152);           // 16384 rows x 136 us
    prm.outp  = (float*)d_out;

    int nb = 0;
    hipOccupancyMaxActiveBlocksPerMultiprocessor(&nb, (const void*)k_fused, 256, 0);
    if (nb < 1) nb = 1;
    unsigned grid = (unsigned)nb * 256u;
    if (grid > 1024u) grid = 1024u;

    void* args[] = { (void*)&prm };
    hipLaunchCooperativeKernel((const void*)k_fused, dim3(grid), dim3(256), args, 0, stream);
}

// Round 9
// 74.415 us; speedup vs baseline: 4.5778x; 4.5778x over previous
//
#include <hip/hip_runtime.h>
#include <stdint.h>

typedef unsigned int u32;
typedef unsigned long long u64;
typedef unsigned short us;
using short8 = __attribute__((ext_vector_type(8))) short;
using us8    = __attribute__((ext_vector_type(8))) us;
using f32x4  = __attribute__((ext_vector_type(4))) float;

#define BT 16
#define NPT 1024

// ---------- bf16 helpers ----------
__device__ __forceinline__ us f2bf(float f) {           // RNE f32 -> bf16
    u32 u = __float_as_uint(f);
    u += 0x7fffu + ((u >> 16) & 1u);
    return (us)(u >> 16);
}
__device__ __forceinline__ float bf2f(us v) { return __uint_as_float(((u32)v) << 16); }
__device__ __forceinline__ u32 packbf(float lo, float hi) {  // validated software pack
    return (u32)f2bf(lo) | ((u32)f2bf(hi) << 16);
}

// ---------- weight prep: conv-a layout (octet-contiguous, neighbor-split K) ----------
// hw k = kt*32 + h*8 + j ; ci = kt*4+h ; p = ci>=NOCT ; q = ci-p*NOCT ; c = q*8+j
// logical channel c: [0,Cfeat) -> ref c+3 ; [Cfeat,Cfeat+3) -> ref c-Cfeat (xyz diff) ; else 0
__device__ void wprep_a(int tid, const float* __restrict__ w, us* __restrict__ dst,
                        int Cfeat, int Creal, int NOCT) {
    int lane = tid & 63, ct = (tid >> 6) & 7, kt = tid >> 9;
    int o = ct * 16 + (lane & 15);
    int h = lane >> 4;
    int ci = kt * 4 + h;
    int p = (ci >= NOCT) ? 1 : 0;
    int q = ci - p * NOCT;
    us8 v;
#pragma unroll
    for (int j = 0; j < 8; ++j) {
        int c = q * 8 + j;
        int ref = (c < Cfeat) ? c + 3 : ((c < Cfeat + 3) ? c - Cfeat : -1);
        v[j] = (ref >= 0) ? f2bf(w[((size_t)o * Creal + ref) * 2 + p]) : (us)0;
    }
    *(us8*)(dst + (size_t)tid * 8) = v;
}

// ---------- weight prep: conv-b/c layout (pair-interleaved K, matches epilogue) ----------
__device__ void wprep_b(int tid, const float* __restrict__ w, us* __restrict__ dst) {
    int lane = tid & 63, ct = (tid >> 6) & 7, kt = tid >> 9;
    int o = ct * 16 + (lane & 15);
    int k0 = kt * 32 + ((lane >> 4) << 3);
    us8 v;
#pragma unroll
    for (int j = 0; j < 8; ++j) v[j] = f2bf(w[(size_t)o * 256 + k0 + j]);
    *(us8*)(dst + (size_t)tid * 8) = v;
}

// ---------- fused select + all prep ----------
// blocks 0..1023: octant select | 1024..1115: weight prep | 1116..1163: xyz copy
// 1164..1227: ptsbf rows | 1228..1291: newbf xyz/pad rows
__global__ __launch_bounds__(256) void k_selprep(
    const float* __restrict__ xyz, const float* __restrict__ pts, u64* __restrict__ keys,
    const float* __restrict__ w1a, us* __restrict__ f1a,
    const float* __restrict__ w1b, us* __restrict__ f1b,
    const float* __restrict__ w1c, us* __restrict__ f1c,
    const float* __restrict__ w2a, us* __restrict__ f2a,
    const float* __restrict__ w2b, us* __restrict__ f2b,
    const float* __restrict__ w2c, us* __restrict__ f2c,
    us* __restrict__ ptsbf, us* __restrict__ newbf, float* __restrict__ outp) {
    const int blk = blockIdx.x, t = threadIdx.x;

    if (blk >= 1024) {
        int u2 = blk - 1024;
        if (u2 < 92) {                                 // weight prep
            if (u2 < 10)      wprep_a(u2 * 256 + t, w1a, f1a, 64, 67, 10);
            else if (u2 < 26) wprep_b((u2 - 10) * 256 + t, w1b, f1b);
            else if (u2 < 42) wprep_b((u2 - 26) * 256 + t, w1c, f1c);
            else if (u2 < 60) wprep_a((u2 - 42) * 256 + t, w2a, f2a, 128, 131, 18);
            else if (u2 < 76) wprep_b((u2 - 60) * 256 + t, w2b, f2b);
            else              wprep_b((u2 - 76) * 256 + t, w2c, f2c);
        } else if (u2 < 140) {                         // xyz passthrough: 12288 float4
            int id = (u2 - 92) * 256 + t;
            ((float4*)outp)[id] = ((const float4*)xyz)[id];
        } else if (u2 < 204) {                         // ptsbf row prep
            int r = (u2 - 140) * 256 + t;
            const float4* pr = (const float4*)(pts + ((size_t)r << 6));
            u32* dst = (u32*)(ptsbf + (size_t)r * 80);
#pragma unroll
            for (int i = 0; i < 16; ++i) {
                float4 f = pr[i];
                dst[2 * i]     = packbf(f.x, f.y);
                dst[2 * i + 1] = packbf(f.z, f.w);
            }
            const float* xr = xyz + (size_t)r * 3;
            dst[32] = packbf(xr[0], xr[1]);
            dst[33] = packbf(xr[2], 0.f);
#pragma unroll
            for (int i = 34; i < 40; ++i) dst[i] = 0u;
        } else {                                       // newbf xyz/pad prep
            int r = (u2 - 204) * 256 + t;
            u32* dst = (u32*)(newbf + (size_t)r * 144);
            const float* xr = xyz + (size_t)r * 3;
            dst[64] = packbf(xr[0], xr[1]);
            dst[65] = packbf(xr[2], 0.f);
#pragma unroll
            for (int i = 66; i < 72; ++i) dst[i] = 0u;
        }
        return;
    }

    // ---- select: blk = ((b*16 + chunk)*4 + nb) ----
    const int b = blk >> 6, chunk = (blk >> 2) & 15, nb = blk & 3;
    const int j0 = chunk * 64;
    __shared__ float sx[192];
    __shared__ float sn[4][64][3];
    __shared__ us lst[4][4096];                        // worst-case-safe capacity

    const float* xb = xyz + (size_t)b * 3072;
    if (t < 192) sx[t] = xb[(size_t)j0 * 3 + t];
    const int n = nb * 256 + t;                        // n within batch
    const int lane = t & 63, wid = t >> 6;
    const float xn = xb[n * 3 + 0], yn = xb[n * 3 + 1], zn = xb[n * 3 + 2];
    sn[wid][lane][0] = xn; sn[wid][lane][1] = yn; sn[wid][lane][2] = zn;
    __syncthreads();

    // pass 1: distance + validity only, wave-compact shortlist
    us* wl = lst[wid];
    u32 cnt = 0;
    for (int jj = 0; jj < 64; ++jj) {
        float dx = __fadd_rn(sx[jj * 3 + 0], -xn);
        float dy = __fadd_rn(sx[jj * 3 + 1], -yn);
        float dz = __fadd_rn(sx[jj * 3 + 2], -zn);
        // exact IEEE f32, no contraction: must match numpy bit-for-bit
        float d = __fadd_rn(__fadd_rn(__fmul_rn(dx, dx), __fmul_rn(dy, dy)), __fmul_rn(dz, dz));
        bool valid = (d > 1e-10f) && (d < 0.04f);
        u64 m = __ballot(valid);
        if (valid) {
            u32 off = __builtin_amdgcn_mbcnt_lo((u32)m, 0);
            off = __builtin_amdgcn_mbcnt_hi((u32)(m >> 32), off);
            wl[cnt + off] = (us)((lane << 6) | jj);
        }
        cnt += (u32)__popcll(m);
    }

    // pass 2: balanced over lanes; exact recompute + direct atomicMin
    const int n0w = nb * 256 + wid * 64;
    u64* kb = keys + (((size_t)b << 10) << 3);
    for (u32 i = lane; i < cnt; i += 64) {
        u32 e = wl[i];
        int nl = e >> 6, jj = e & 63;
        float dx = __fadd_rn(sx[jj * 3 + 0], -sn[wid][nl][0]);
        float dy = __fadd_rn(sx[jj * 3 + 1], -sn[wid][nl][1]);
        float dz = __fadd_rn(sx[jj * 3 + 2], -sn[wid][nl][2]);
        float d = __fadd_rn(__fadd_rn(__fmul_rn(dx, dx), __fmul_rn(dy, dy)), __fmul_rn(dz, dz));
        int oct = ((int)__fadd_rn(dx, 1.0f)) * 4 + ((int)__fadd_rn(dy, 1.0f)) * 2 +
                  ((int)__fadd_rn(dz, 1.0f));
        u64 key = ((u64)__float_as_uint(d) << 32) | (u32)(j0 + jj);
        atomicMin(&kb[((size_t)(n0w + nl) << 3) + oct], key);
    }

    if (chunk == 0) {                                  // self-fallback keys
        u64 selfkey = ((u64)__float_as_uint(0.04f) << 32) | (u32)n;
        u64* kp = kb + ((size_t)n << 3);
#pragma unroll
        for (int o = 0; o < 8; ++o) atomicMin(&kp[o], selfkey);
    }
}

// ---------- fused stage: 1-load gather -> conv-a -> conv-b -> conv-c ----------
// Block = 64 conv-a rows = 16 groups; 1024 blocks; LDS 24KB.
template<int S>
__global__ __launch_bounds__(256, 4) void k_stage(
    const float* __restrict__ pts, const us* __restrict__ feat,
    const u32* __restrict__ keys32,
    const us* __restrict__ wfa, const float* __restrict__ ba,
    const us* __restrict__ wfb, const float* __restrict__ bb,
    const us* __restrict__ wfc, const float* __restrict__ bc,
    us* __restrict__ newbf_out, float* __restrict__ outp) {
    constexpr int KTA  = (S == 1) ? 5 : 9;
    constexpr int NOCT = (S == 1) ? 10 : 18;
    constexpr int RSTR = (S == 1) ? 80 : 144;
    constexpr int FIXC = (S == 1) ? 64 : 128;          // bf16-xyz slot base
    constexpr int FIXQ = FIXC / 8;
    __shared__ us abuf[2 * 8 * 512];     // conv-b A fragments: 2 m-tiles, 16KB
    __shared__ us cbuf[1 * 8 * 512];     // conv-c A fragments: 1 m-tile, 8KB

    const int t = threadIdx.x, wid = t >> 6, lane = t & 63;
    const int li = lane & 15, h = lane >> 4;
    const int m0 = blockIdx.x * 64;      // conv-a global row base
    const int g0 = blockIdx.x * 16;      // 16 groups per block
    const int b = blockIdx.x >> 6;
    const us* fb = feat + (size_t)b * NPT * RSTR;

    // this thread's conv-a row: m-tile = wid
    const int m = m0 + wid * 16 + li;
    const int g = m >> 2, pos = m & 3;
    const int J0 = (int)keys32[((size_t)g * 8 + 2 * pos) * 2];
    const int J1 = (int)keys32[((size_t)g * 8 + 2 * pos + 1) * 2];
    const int N = g & (NPT - 1);

    const us* row0 = fb + (size_t)J0 * RSTR;
    const us* row1 = fb + (size_t)J1 * RSTR;
    us8 xn8 = *(const us8*)(fb + (size_t)N * RSTR + FIXC);
    const float xn0 = bf2f(xn8[0]), xn1 = bf2f(xn8[1]), xn2 = bf2f(xn8[2]);

    // ---- conv-a: 1 aligned 16B gather load per kt, bias in acc ----
    f32x4 acc[8];
#pragma unroll
    for (int ct = 0; ct < 8; ++ct) {
        float bv = ba[ct * 16 + li];
        acc[ct] = f32x4{bv, bv, bv, bv};
    }
    for (int kt = 0; kt < KTA; ++kt) {
        int ci = kt * 4 + h;
        int q = (ci >= NOCT) ? ci - NOCT : ci;
        const us* rp = (ci >= NOCT) ? row1 : row0;
        us8 v = *(const us8*)(rp + q * 8);
        if (q == FIXQ) {                               // xyz-diff fixup (lane-masked)
            v[0] = f2bf(__fadd_rn(bf2f(v[0]), -xn0));
            v[1] = f2bf(__fadd_rn(bf2f(v[1]), -xn1));
            v[2] = f2bf(__fadd_rn(bf2f(v[2]), -xn2));
        }
        short8 a = __builtin_bit_cast(short8, v);
        const us* wk = wfa + (size_t)kt * 4096;
#pragma unroll
        for (int ct = 0; ct < 8; ++ct) {
            short8 w = *(const short8*)(wk + ((size_t)ct * 64 + lane) * 8);
            acc[ct] = __builtin_amdgcn_mfma_f32_16x16x32_bf16(a, w, acc[ct], 0, 0, 0);
        }
    }
    {   // pair-transpose epilogue -> abuf (validated formula; software pack)
        u32* dst = (u32*)abuf;
        int mbase = wid * 16 + (h << 2);
        int mr0 = mbase >> 1, mr1 = mr0 + 1;
#pragma unroll
        for (int ct = 0; ct < 8; ++ct) {
            f32x4 av = acc[ct];
            u32 p0 = packbf(av[0], av[1]);
            u32 p1 = packbf(av[2], av[3]);
            dst[((mr0 >> 4) * 8 + ct) * 256 + ((mr0 & 15) + ((li >> 2) << 4)) * 4 + (li & 3)] = p0;
            dst[((mr1 >> 4) * 8 + ct) * 256 + ((mr1 & 15) + ((li >> 2) << 4)) * 4 + (li & 3)] = p1;
        }
    }
    __syncthreads();

    // ---- conv-b: wave -> m-tile (wid>>1), ct block (wid&1)*4..+3 ----
    const int mtB = wid >> 1, ctbB = (wid & 1) * 4;
    f32x4 accB[4];
#pragma unroll
    for (int cc = 0; cc < 4; ++cc) {
        float bv = bb[(ctbB + cc) * 16 + li];
        accB[cc] = f32x4{bv, bv, bv, bv};
    }
    for (int kt = 0; kt < 8; ++kt) {
        short8 a = *(const short8*)(abuf + (((size_t)mtB * 8 + kt) * 64 + lane) * 8);
        const us* wk = wfb + ((size_t)kt * 8 + ctbB) * 512;
#pragma unroll
        for (int cc = 0; cc < 4; ++cc) {
            short8 w = *(const short8*)(wk + ((size_t)cc * 64 + lane) * 8);
            accB[cc] = __builtin_amdgcn_mfma_f32_16x16x32_bf16(a, w, accB[cc], 0, 0, 0);
        }
    }
    {   // -> cbuf (conv-c rows 0..15, single m-tile)
        u32* dst = (u32*)cbuf;
        int mbase = mtB * 16 + (h << 2);
        int mr0 = mbase >> 1, mr1 = mr0 + 1;
#pragma unroll
        for (int cc = 0; cc < 4; ++cc) {
            int ct = ctbB + cc;
            f32x4 av = accB[cc];
            u32 p0 = packbf(av[0], av[1]);
            u32 p1 = packbf(av[2], av[3]);
            dst[ct * 256 + (mr0 + ((li >> 2) << 4)) * 4 + (li & 3)] = p0;
            dst[ct * 256 + (mr1 + ((li >> 2) << 4)) * 4 + (li & 3)] = p1;
        }
    }
    __syncthreads();

    // ---- conv-c: wave -> ct pair wid*2..+1, single m-tile ----
    f32x4 accC[2];
#pragma unroll
    for (int cc = 0; cc < 2; ++cc) {
        float bv = bc[(wid * 2 + cc) * 16 + li];
        accC[cc] = f32x4{bv, bv, bv, bv};
    }
    for (int kt = 0; kt < 8; ++kt) {
        short8 a = *(const short8*)(cbuf + ((size_t)kt * 64 + lane) * 8);
        const us* wk = wfc + ((size_t)kt * 8 + wid * 2) * 512;
#pragma unroll
        for (int cc = 0; cc < 2; ++cc) {
            short8 w = *(const short8*)(wk + ((size_t)cc * 64 + lane) * 8);
            accC[cc] = __builtin_amdgcn_mfma_f32_16x16x32_bf16(a, w, accC[cc], 0, 0, 0);
        }
    }
#pragma unroll
    for (int cc = 0; cc < 2; ++cc) {
        int o = (wid * 2 + cc) * 16 + li;
#pragma unroll
        for (int r = 0; r < 4; ++r) {
            int gg = g0 + h * 4 + r;
            float val = accC[cc][r];
            if constexpr (S == 1)
                newbf_out[(size_t)gg * 144 + o] = f2bf(val);   // slot o (new layout)
            else
                outp[(size_t)49152 + (size_t)gg * 192 + o] = fmaxf(val, 0.f);
        }
    }

    if constexpr (S == 2) {
        // relu(points) tail: 16 groups x 16 float4 each
        int r = t >> 4, q = t & 15;
        float4 v = ((const float4*)(pts + ((size_t)(g0 + r) << 6)))[q];
        v.x = fmaxf(v.x, 0.0f);
        v.y = fmaxf(v.y, 0.0f);
        v.z = fmaxf(v.z, 0.0f);
        v.w = fmaxf(v.w, 0.0f);
        *(float4*)(outp + 49152 + (size_t)(g0 + r) * 192 + 128 + q * 4) = v;
    }
}

extern "C" void kernel_launch(void* const* d_in, const int* in_sizes, int n_in,
                              void* d_out, int out_size, void* d_ws, size_t ws_size,
                              hipStream_t stream) {
    const float* xyz = (const float*)d_in[0];
    const float* pts = (const float*)d_in[1];
    const float* w1a = (const float*)d_in[2];
    const float* b1a = (const float*)d_in[3];
    const float* w1b = (const float*)d_in[4];
    const float* b1b = (const float*)d_in[5];
    const float* w1c = (const float*)d_in[6];
    const float* b1c = (const float*)d_in[7];
    const float* w2a = (const float*)d_in[8];
    const float* b2a = (const float*)d_in[9];
    const float* w2b = (const float*)d_in[10];
    const float* b2b = (const float*)d_in[11];
    const float* w2c = (const float*)d_in[12];
    const float* b2c = (const float*)d_in[13];
    float* outp = (float*)d_out;

    char* ws = (char*)d_ws;
    u64* keys = (u64*)ws;                            // 1 MB
    const u32* keys32 = (const u32*)ws;
    us* wf1a = (us*)(ws + 1048576);                  // 40 KB  (KT=5)
    us* wf1b = (us*)(ws + 1089536);                  // 64 KB  (KT=8)
    us* wf1c = (us*)(ws + 1155072);                  // 64 KB
    us* wf2a = (us*)(ws + 1220608);                  // 72 KB  (KT=9)
    us* wf2b = (us*)(ws + 1294336);                  // 64 KB
    us* wf2c = (us*)(ws + 1359872);                  // 64 KB
    us* ptsbf = (us*)(ws + 2097152);                 // 16384 x 80 us = 2.62 MB
    us* newbf = (us*)(ws + 5242880);                 // 16384 x 144 us = 4.72 MB

    k_selprep<<<1292, 256, 0, stream>>>(xyz, pts, keys, w1a, wf1a, w1b, wf1b, w1c, wf1c,
                                        w2a, wf2a, w2b, wf2b, w2c, wf2c,
                                        ptsbf, newbf, outp);
    k_stage<1><<<1024, 256, 0, stream>>>(pts, ptsbf, keys32,
                                         wf1a, b1a, wf1b, b1b, wf1c, b1c, newbf, nullptr);
    k_stage<2><<<1024, 256, 0, stream>>>(pts, newbf, keys32,
                                         wf2a, b2a, wf2b, b2b, wf2c, b2c, nullptr, outp);
}